// Round 4
// baseline (582.346 us; speedup 1.0000x reference)
//
#include <hip/hip_runtime.h>

// Convattn: B=16, N=740 (256+484), C=768, H=12, hd=64. Inputs/outputs fp32.
// ws: XB/QB/Q/K/V/CTX bf16 (V aliases QB, CTX aliases XB), BIAS2 bf16
// repacked [h][row][jb][ln][nt], WT bf16 (4 transposed weights; q-plane
// pre-scaled by 0.125).

typedef unsigned short u16;
typedef short bf16x8 __attribute__((ext_vector_type(8)));
typedef float f32x4 __attribute__((ext_vector_type(4)));

#define BSZ   16
#define NTOK  740
#define NTMP  256
#define NTGT  484
#define DIMC  768
#define NHEAD 12
#define HDIM  64
#define MROWS (BSZ*NTOK)      // 11840
#define SMAX  16.0f           // fixed softmax max (scores bounded ~|6|)

__device__ __forceinline__ float bf2f(u16 u) {
    return __uint_as_float(((unsigned int)u) << 16);
}
__device__ __forceinline__ float bflo(unsigned int u) {
    return __uint_as_float(u << 16);
}
__device__ __forceinline__ float bfhi(unsigned int u) {
    return __uint_as_float(u & 0xffff0000u);
}
__device__ __forceinline__ u16 f2bf(float f) {
    unsigned int u = __float_as_uint(f);
    u += 0x7fffu + ((u >> 16) & 1u);   // RNE
    return (u16)(u >> 16);
}

// async 16B global -> LDS (gfx950). LDS dest must be base + lane*16.
__device__ __forceinline__ void gl_lds16(const u16* g, u16* l) {
    __builtin_amdgcn_global_load_lds(
        (const __attribute__((address_space(1))) unsigned int*)(unsigned long long)g,
        (__attribute__((address_space(3))) unsigned int*)(unsigned int)(unsigned long long)l,
        16, 0, 0);
}

// repacked bias offset: [h][i][jb][ln][nt]
__device__ __forceinline__ size_t b2off(int h, int i, int j) {
    return ((size_t)(h * NTOK + i)) * 768 + ((j >> 6) << 6) + ((j & 15) << 2) + ((j >> 4) & 3);
}

// ---------------------------------------------------------------------------
// fp32 -> bf16 pre-convert: XB = bf16(x); QB = bf16(concat(temp_q, target_q))
// grid 4440x256, one 8-elem chunk per thread per stream.
// ---------------------------------------------------------------------------
__global__ __launch_bounds__(256) void convert_qx(
    const float* __restrict__ x, const float* __restrict__ tq,
    const float* __restrict__ gq, u16* __restrict__ XB, u16* __restrict__ QB)
{
    int c = blockIdx.x * 256 + threadIdx.x;           // 0 .. 1,136,640-1
    if (c >= MROWS * DIMC / 8) return;
    {
        const float* s = x + (size_t)c * 8;
        float4 p0 = *(const float4*)s, p1 = *(const float4*)(s + 4);
        u16 e[8] = {f2bf(p0.x), f2bf(p0.y), f2bf(p0.z), f2bf(p0.w),
                    f2bf(p1.x), f2bf(p1.y), f2bf(p1.z), f2bf(p1.w)};
        *(uint4*)(XB + (size_t)c * 8) = *(uint4*)e;
    }
    {
        int row = c / 96, cc = (c - row * 96) * 8;
        int b = row / NTOK, n = row - b * NTOK;
        const float* s = (n < NTMP)
                       ? tq + ((size_t)(b * NTMP + n)) * DIMC + cc
                       : gq + ((size_t)(b * NTGT + (n - NTMP))) * DIMC + cc;
        float4 p0 = *(const float4*)s, p1 = *(const float4*)(s + 4);
        u16 e[8] = {f2bf(p0.x), f2bf(p0.y), f2bf(p0.z), f2bf(p0.w),
                    f2bf(p1.x), f2bf(p1.y), f2bf(p1.z), f2bf(p1.w)};
        *(uint4*)(QB + (size_t)row * DIMC + cc) = *(uint4*)e;
    }
}

// ---------------------------------------------------------------------------
// Weight transpose + fp32->bf16: Wt[z][out][in] = w_z[in][out]; z=0 scaled 1/8
// ---------------------------------------------------------------------------
__global__ __launch_bounds__(256) void transpose_w(
    const float* __restrict__ w0, const float* __restrict__ w1,
    const float* __restrict__ w2, const float* __restrict__ w3,
    u16* __restrict__ Wt)
{
    __shared__ float T[64][65];
    const float* src = (blockIdx.z == 0) ? w0 : (blockIdx.z == 1) ? w1
                     : (blockIdx.z == 2) ? w2 : w3;
    const float scale = (blockIdx.z == 0) ? 0.125f : 1.0f;
    u16* dst = Wt + (size_t)blockIdx.z * DIMC * DIMC;
    int out0 = blockIdx.x * 64, in0 = blockIdx.y * 64;
    int tid = threadIdx.x;
    #pragma unroll
    for (int l = 0; l < 4; l++) {
        int u = tid + (l << 8);
        int r = u >> 4, c4 = (u & 15) << 2;
        float4 p = *(const float4*)(src + (size_t)(in0 + r) * DIMC + out0 + c4);
        T[r][c4] = p.x; T[r][c4 + 1] = p.y; T[r][c4 + 2] = p.z; T[r][c4 + 3] = p.w;
    }
    __syncthreads();
    #pragma unroll
    for (int l = 0; l < 2; l++) {
        int u = tid + (l << 8);
        int r = u >> 3, c8 = (u & 7) << 3;
        u16 e[8];
        #pragma unroll
        for (int i = 0; i < 8; i++) e[i] = f2bf(T[c8 + i][r] * scale);
        *(uint4*)(dst + (size_t)(out0 + r) * DIMC + in0 + c8) = *(uint4*)e;
    }
}

// ---------------------------------------------------------------------------
// Bias diagonal blocks + column padding into repacked layout.
// ---------------------------------------------------------------------------
__global__ __launch_bounds__(256) void bias_diag(
    const float* __restrict__ rpb, const float* __restrict__ rpbt,
    const int* __restrict__ tidx, const int* __restrict__ gidx,
    u16* __restrict__ bias)
{
    int j = blockIdx.x * 256 + threadIdx.x;   // 0..767
    int i = blockIdx.y;
    if (j >= 768) return;
    u16 vals[NHEAD];
    if (j >= NTOK) {
        u16 neg = f2bf(-1e30f);
        #pragma unroll
        for (int h = 0; h < NHEAD; h++) vals[h] = neg;
    } else if (i < NTMP && j < NTMP) {
        int idx = tidx[i * NTMP + j];
        #pragma unroll
        for (int h = 0; h < NHEAD; h++) vals[h] = f2bf(rpbt[idx * NHEAD + h]);
    } else if (i >= NTMP && j >= NTMP) {
        int idx = gidx[(i - NTMP) * NTGT + (j - NTMP)];
        #pragma unroll
        for (int h = 0; h < NHEAD; h++) vals[h] = f2bf(rpb[idx * NHEAD + h]);
    } else {
        return;  // cross region handled by bias_cross
    }
    #pragma unroll
    for (int h = 0; h < NHEAD; h++) bias[b2off(h, i, j)] = vals[h];
}

// ---------------------------------------------------------------------------
// Cross-bias MLP, computed once per (g,t), scattered to both cross blocks.
// ---------------------------------------------------------------------------
__global__ __launch_bounds__(256) void bias_cross(
    const float* __restrict__ w1, const float* __restrict__ b1,
    const float* __restrict__ w2, const float* __restrict__ b2,
    const float* __restrict__ tab, u16* __restrict__ bias)
{
    int g = blockIdx.x, t = threadIdx.x;
    float a  = tab[(g * NTMP + t) * 2 + 0];
    float bb = tab[(g * NTMP + t) * 2 + 1];
    float acc[NHEAD];
    #pragma unroll
    for (int h = 0; h < NHEAD; h++) acc[h] = b2[h];
    for (int k = 0; k < 512; k++) {
        float hid = fmaxf(a * w1[k] + bb * w1[512 + k] + b1[k], 0.0f);
        #pragma unroll
        for (int h = 0; h < NHEAD; h++) acc[h] += hid * w2[k * NHEAD + h];
    }
    #pragma unroll
    for (int h = 0; h < NHEAD; h++) {
        u16 v = f2bf(acc[h]);
        bias[b2off(h, t, NTMP + g)] = v;   // top-right
        bias[b2off(h, NTMP + g, t)] = v;   // bottom-left
    }
}

// ---------------------------------------------------------------------------
// bf16 MFMA GEMM, m97-style: BK=32, chunk-column-major LDS, global_load_lds.
// MODE 0: out bf16 -> C0. MODE 1 (KV fused, N=1536): n<768 -> C0, else C1.
// MODE 2: out fp32 + pb -> Cf.
// ---------------------------------------------------------------------------
template<int MODE>
__global__ __launch_bounds__(256) void gemm_bf16(
    const u16* __restrict__ A, const u16* __restrict__ Wt,
    const float* __restrict__ pb, u16* __restrict__ C0,
    u16* __restrict__ C1, float* __restrict__ Cf)
{
    __shared__ __align__(16) u16 As[4096];   // chunk (c8,r): offset (c8*128+r)*8
    __shared__ __align__(16) u16 Bs[4096];
    const int tid = threadIdx.x;
    const int lane = tid & 63, w = tid >> 6;
    const int quad = lane >> 4, ln = lane & 15;
    const int m0 = blockIdx.y << 7, n0g = blockIdx.x << 7;
    const int wm = (w >> 1) << 6, wn = (w & 1) << 6;
    const u16* Wbase = Wt + (size_t)n0g * DIMC;

    f32x4 acc[4][4];
    #pragma unroll
    for (int i = 0; i < 4; i++)
        #pragma unroll
        for (int j = 0; j < 4; j++)
            acc[i][j] = (f32x4){0.f, 0.f, 0.f, 0.f};

    for (int k0 = 0; k0 < DIMC; k0 += 32) {
        __syncthreads();
        #pragma unroll
        for (int l = 0; l < 2; l++) {
            int u = tid + (l << 8);
            int c8 = u >> 7, r = u & 127;
            int grow = m0 + r; if (grow >= MROWS) grow = MROWS - 1;
            gl_lds16(A + (size_t)grow * DIMC + k0 + c8 * 8, As + u * 8);
            gl_lds16(Wbase + (size_t)r * DIMC + k0 + c8 * 8, Bs + u * 8);
        }
        __syncthreads();
        bf16x8 af[4], bfr[4];
        #pragma unroll
        for (int mt = 0; mt < 4; mt++)
            af[mt] = *(const bf16x8*)&As[(quad * 128 + wm + mt * 16 + ln) * 8];
        #pragma unroll
        for (int nt = 0; nt < 4; nt++)
            bfr[nt] = *(const bf16x8*)&Bs[(quad * 128 + wn + nt * 16 + ln) * 8];
        #pragma unroll
        for (int mt = 0; mt < 4; mt++)
            #pragma unroll
            for (int nt = 0; nt < 4; nt++)
                acc[mt][nt] = __builtin_amdgcn_mfma_f32_16x16x32_bf16(
                    af[mt], bfr[nt], acc[mt][nt], 0, 0, 0);
    }

    u16* Cb = C0;
    int col0 = n0g;
    if (MODE == 1 && n0g >= DIMC) { Cb = C1; col0 = n0g - DIMC; }

    #pragma unroll
    for (int mt = 0; mt < 4; mt++) {
        #pragma unroll
        for (int reg = 0; reg < 4; reg++) {
            int grow = m0 + wm + mt * 16 + (quad << 2) + reg;
            if (grow >= MROWS) continue;
            #pragma unroll
            for (int nt = 0; nt < 4; nt++) {
                int gcol = col0 + wn + nt * 16 + ln;
                float v = acc[mt][nt][reg];
                if (MODE == 2) {
                    Cf[(size_t)grow * DIMC + gcol] = v + pb[gcol];
                } else {
                    Cb[(size_t)grow * DIMC + gcol] = f2bf(v);
                }
            }
        }
    }
}

// ---------------------------------------------------------------------------
// Flash MFMA attention, fixed-max softmax. Block: (qtile, h, b-pair).
// 64 Q-rows, 4 waves x 16 rows; K/V tiles of 64. grid (12, 12, 8).
// Q weights pre-scaled 0.125, so S = QK^T + bias directly.
// ---------------------------------------------------------------------------
__global__ __launch_bounds__(256) void attn_mfma(
    const u16* __restrict__ Qg, const u16* __restrict__ Kg,
    const u16* __restrict__ Vg, const u16* __restrict__ bias,
    u16* __restrict__ ctx)
{
    __shared__ __align__(16) u16 Ks[64][72];
    __shared__ __align__(16) u16 Vt[64][72];
    __shared__ __align__(16) u16 Pw[4][16][72];

    const int tid = threadIdx.x;
    const int lane = tid & 63, w = tid >> 6;
    const int quad = lane >> 4, ln = lane & 15;
    const int h = blockIdx.y;
    const int q0 = blockIdx.x << 6;
    const int rbase = q0 + (w << 4) + (quad << 2);
    const u16* bp = bias + ((size_t)h * NTOK) * 768;

    for (int bi = 0; bi < 2; bi++) {
        const int b = (blockIdx.z << 1) + bi;

        bf16x8 aq[2];
        {
            int qrow = q0 + (w << 4) + ln;
            #pragma unroll
            for (int kp = 0; kp < 2; kp++) {
                uint4 p = make_uint4(0u, 0u, 0u, 0u);
                if (qrow < NTOK)
                    p = *(const uint4*)(Qg + ((size_t)(b * NTOK + qrow)) * DIMC
                                        + h * HDIM + kp * 32 + (quad << 3));
                aq[kp] = *(const bf16x8*)&p;
            }
        }

        float rs[4] = {0.f, 0.f, 0.f, 0.f};
        f32x4 O[4];
        #pragma unroll
        for (int dt = 0; dt < 4; dt++) O[dt] = (f32x4){0.f, 0.f, 0.f, 0.f};

        for (int j0 = 0; j0 < NTOK; j0 += 64) {
            __syncthreads();
            #pragma unroll
            for (int l = 0; l < 2; l++) {
                int u = tid + (l << 8);
                int jr = u >> 3, c8 = (u & 7) << 3;
                int krow = j0 + jr;
                uint4 p = make_uint4(0u, 0u, 0u, 0u);
                if (krow < NTOK)
                    p = *(const uint4*)(Kg + ((size_t)(b * NTOK + krow)) * DIMC + h * HDIM + c8);
                *(uint4*)&Ks[jr][c8] = p;
            }
            #pragma unroll
            for (int l = 0; l < 2; l++) {
                int u = tid + (l << 8);
                int jr = u >> 3, d0 = (u & 7) << 3;
                int vrow = j0 + jr;
                uint4 p = make_uint4(0u, 0u, 0u, 0u);
                if (vrow < NTOK)
                    p = *(const uint4*)(Vg + ((size_t)(b * NTOK + vrow)) * DIMC + h * HDIM + d0);
                const u16* pe = (const u16*)&p;
                #pragma unroll
                for (int i = 0; i < 8; i++) Vt[d0 + i][jr] = pe[i];
            }
            __syncthreads();

            // S = (Q/8) K^T
            f32x4 s[4];
            #pragma unroll
            for (int nt = 0; nt < 4; nt++) {
                f32x4 c = (f32x4){0.f, 0.f, 0.f, 0.f};
                #pragma unroll
                for (int kp = 0; kp < 2; kp++) {
                    bf16x8 bk = *(const bf16x8*)&Ks[nt * 16 + ln][kp * 32 + (quad << 3)];
                    c = __builtin_amdgcn_mfma_f32_16x16x32_bf16(aq[kp], bk, c, 0, 0, 0);
                }
                s[nt] = c;
            }
            // + bias (vectorized repacked load), exp(s - SMAX), accumulate sums
            #pragma unroll
            for (int reg = 0; reg < 4; reg++) {
                int rr = rbase + reg; if (rr >= NTOK) rr = NTOK - 1;
                uint2 bv = *(const uint2*)(bp + (size_t)rr * 768 + j0 + (ln << 2));
                float p0 = __expf(s[0][reg] + bflo(bv.x) - SMAX);
                float p1 = __expf(s[1][reg] + bfhi(bv.x) - SMAX);
                float p2 = __expf(s[2][reg] + bflo(bv.y) - SMAX);
                float p3 = __expf(s[3][reg] + bfhi(bv.y) - SMAX);
                s[0][reg] = p0; s[1][reg] = p1; s[2][reg] = p2; s[3][reg] = p3;
                rs[reg] += p0 + p1 + p2 + p3;
            }
            // P -> LDS (C layout -> A layout), wave-private
            #pragma unroll
            for (int nt = 0; nt < 4; nt++)
                #pragma unroll
                for (int reg = 0; reg < 4; reg++)
                    Pw[w][(quad << 2) + reg][nt * 16 + ln] = f2bf(s[nt][reg]);
            // O += P V
            bf16x8 ap[2];
            #pragma unroll
            for (int kp = 0; kp < 2; kp++)
                ap[kp] = *(const bf16x8*)&Pw[w][ln][kp * 32 + (quad << 3)];
            #pragma unroll
            for (int dt = 0; dt < 4; dt++)
                #pragma unroll
                for (int kp = 0; kp < 2; kp++) {
                    bf16x8 bv = *(const bf16x8*)&Vt[dt * 16 + ln][kp * 32 + (quad << 3)];
                    O[dt] = __builtin_amdgcn_mfma_f32_16x16x32_bf16(ap[kp], bv, O[dt], 0, 0, 0);
                }
        }

        // final row-sum reduce across the 16-lane group, then normalize+store
        #pragma unroll
        for (int reg = 0; reg < 4; reg++) {
            float t = rs[reg];
            #pragma unroll
            for (int mk = 8; mk >= 1; mk >>= 1) t += __shfl_xor(t, mk);
            rs[reg] = 1.0f / t;
        }
        #pragma unroll
        for (int reg = 0; reg < 4; reg++) {
            int row = rbase + reg;
            if (row < NTOK) {
                #pragma unroll
                for (int dt = 0; dt < 4; dt++)
                    ctx[((size_t)(b * NTOK + row)) * DIMC + h * HDIM + dt * 16 + ln]
                        = f2bf(O[dt][reg] * rs[reg]);
            }
        }
    }
}

// ---------------------------------------------------------------------------
extern "C" void kernel_launch(void* const* d_in, const int* in_sizes, int n_in,
                              void* d_out, int out_size, void* d_ws, size_t ws_size,
                              hipStream_t stream)
{
    const float* x        = (const float*)d_in[0];
    const float* temp_q   = (const float*)d_in[1];
    const float* target_q = (const float*)d_in[2];
    const float* q_w      = (const float*)d_in[3];
    const float* k_w      = (const float*)d_in[4];
    const float* v_w      = (const float*)d_in[5];
    const float* proj_w   = (const float*)d_in[6];
    const float* proj_b   = (const float*)d_in[7];
    const float* rpb      = (const float*)d_in[8];
    const float* rpbt     = (const float*)d_in[9];
    const float* pw1      = (const float*)d_in[10];
    const float* pb1      = (const float*)d_in[11];
    const float* pw2      = (const float*)d_in[12];
    const float* pb2      = (const float*)d_in[13];
    const float* tab      = (const float*)d_in[14];
    const int*   tidx     = (const int*)d_in[15];
    const int*   gidx     = (const int*)d_in[16];
    float* out = (float*)d_out;

    char* ws = (char*)d_ws;
    const size_t S = (size_t)MROWS * DIMC * sizeof(u16);          // 18,186,240
    const size_t SZB = (size_t)NHEAD * NTOK * 768 * sizeof(u16);  // 13,639,680
    u16* XB    = (u16*)(ws);           // also CTX (aliased, after KV gemm)
    u16* QB    = (u16*)(ws + S);       // also V (aliased, after Q gemm)
    u16* Q     = (u16*)(ws + 2 * S);
    u16* K     = (u16*)(ws + 3 * S);
    u16* V     = QB;
    u16* CTX   = XB;
    u16* BIAS2 = (u16*)(ws + 4 * S);
    u16* WT    = (u16*)(ws + 4 * S + SZB);                        // 4 x 768 x 768

    convert_qx<<<dim3(4440), 256, 0, stream>>>(x, temp_q, target_q, XB, QB);
    transpose_w<<<dim3(12, 12, 4), 256, 0, stream>>>(q_w, k_w, v_w, proj_w, WT);
    bias_diag<<<dim3(3, 740), 256, 0, stream>>>(rpb, rpbt, tidx, gidx, BIAS2);
    bias_cross<<<dim3(484), 256, 0, stream>>>(pw1, pb1, pw2, pb2, tab, BIAS2);

    const u16* WTq = WT;
    const u16* WTkv = WT + (size_t)DIMC * DIMC;       // k plane, v plane adjacent
    const u16* WTp = WT + 3 * (size_t)DIMC * DIMC;

    gemm_bf16<0><<<dim3(6, 93), 256, 0, stream>>>(QB, WTq, nullptr, Q, nullptr, nullptr);
    gemm_bf16<1><<<dim3(12, 93), 256, 0, stream>>>(XB, WTkv, nullptr, K, V, nullptr);
    attn_mfma<<<dim3(12, 12, 8), 256, 0, stream>>>(Q, K, V, BIAS2, CTX);
    gemm_bf16<2><<<dim3(6, 93), 256, 0, stream>>>(CTX, WTp, proj_b, nullptr, nullptr, out);
}

// Round 5
// 506.434 us; speedup vs baseline: 1.1499x; 1.1499x over previous
//
#include <hip/hip_runtime.h>

// Convattn: B=16, N=740 (256+484), C=768, H=12, hd=64. Inputs/outputs fp32.
// ws: XB/QB/Q/K/V/CTX bf16 (V aliases QB, CTX aliases XB), BIAS2 bf16
// repacked [h][row][jb][ln][nt], WT bf16 (q-plane pre-scaled 0.125).

typedef unsigned short u16;
typedef short bf16x8 __attribute__((ext_vector_type(8)));
typedef float f32x4 __attribute__((ext_vector_type(4)));

#define BSZ   16
#define NTOK  740
#define NTMP  256
#define NTGT  484
#define DIMC  768
#define NHEAD 12
#define HDIM  64
#define MROWS (BSZ*NTOK)      // 11840
#define SMAX  16.0f           // fixed softmax max (scores bounded ~|6|)
#define VSTR  66              // odd-dword V stride: banks spread on transpose writes

__device__ __forceinline__ float bf2f(u16 u) {
    return __uint_as_float(((unsigned int)u) << 16);
}
__device__ __forceinline__ float bflo(unsigned int u) {
    return __uint_as_float(u << 16);
}
__device__ __forceinline__ float bfhi(unsigned int u) {
    return __uint_as_float(u & 0xffff0000u);
}
__device__ __forceinline__ u16 f2bf(float f) {
    unsigned int u = __float_as_uint(f);
    u += 0x7fffu + ((u >> 16) & 1u);   // RNE
    return (u16)(u >> 16);
}

// async 16B global -> LDS (gfx950). LDS dest must be wave base + lane*16.
__device__ __forceinline__ void gl_lds16(const u16* g, u16* l) {
    __builtin_amdgcn_global_load_lds(
        (const __attribute__((address_space(1))) unsigned int*)(unsigned long long)g,
        (__attribute__((address_space(3))) unsigned int*)(unsigned int)(unsigned long long)l,
        16, 0, 0);
}

// repacked bias offset: [h][i][jb][ln][nt]
__device__ __forceinline__ size_t b2off(int h, int i, int j) {
    return ((size_t)(h * NTOK + i)) * 768 + ((j >> 6) << 6) + ((j & 15) << 2) + ((j >> 4) & 3);
}

// ---------------------------------------------------------------------------
// fp32 -> bf16 pre-convert: XB = bf16(x); QB = bf16(concat(temp_q, target_q))
// ---------------------------------------------------------------------------
__global__ __launch_bounds__(256) void convert_qx(
    const float* __restrict__ x, const float* __restrict__ tq,
    const float* __restrict__ gq, u16* __restrict__ XB, u16* __restrict__ QB)
{
    int c = blockIdx.x * 256 + threadIdx.x;
    if (c >= MROWS * DIMC / 8) return;
    {
        const float* s = x + (size_t)c * 8;
        float4 p0 = *(const float4*)s, p1 = *(const float4*)(s + 4);
        u16 e[8] = {f2bf(p0.x), f2bf(p0.y), f2bf(p0.z), f2bf(p0.w),
                    f2bf(p1.x), f2bf(p1.y), f2bf(p1.z), f2bf(p1.w)};
        *(uint4*)(XB + (size_t)c * 8) = *(uint4*)e;
    }
    {
        int row = c / 96, cc = (c - row * 96) * 8;
        int b = row / NTOK, n = row - b * NTOK;
        const float* s = (n < NTMP)
                       ? tq + ((size_t)(b * NTMP + n)) * DIMC + cc
                       : gq + ((size_t)(b * NTGT + (n - NTMP))) * DIMC + cc;
        float4 p0 = *(const float4*)s, p1 = *(const float4*)(s + 4);
        u16 e[8] = {f2bf(p0.x), f2bf(p0.y), f2bf(p0.z), f2bf(p0.w),
                    f2bf(p1.x), f2bf(p1.y), f2bf(p1.z), f2bf(p1.w)};
        *(uint4*)(QB + (size_t)row * DIMC + cc) = *(uint4*)e;
    }
}

// ---------------------------------------------------------------------------
// Weight transpose + fp32->bf16: Wt[z][out][in] = w_z[in][out]; z=0 scaled 1/8
// ---------------------------------------------------------------------------
__global__ __launch_bounds__(256) void transpose_w(
    const float* __restrict__ w0, const float* __restrict__ w1,
    const float* __restrict__ w2, const float* __restrict__ w3,
    u16* __restrict__ Wt)
{
    __shared__ float T[64][65];
    const float* src = (blockIdx.z == 0) ? w0 : (blockIdx.z == 1) ? w1
                     : (blockIdx.z == 2) ? w2 : w3;
    const float scale = (blockIdx.z == 0) ? 0.125f : 1.0f;
    u16* dst = Wt + (size_t)blockIdx.z * DIMC * DIMC;
    int out0 = blockIdx.x * 64, in0 = blockIdx.y * 64;
    int tid = threadIdx.x;
    #pragma unroll
    for (int l = 0; l < 4; l++) {
        int u = tid + (l << 8);
        int r = u >> 4, c4 = (u & 15) << 2;
        float4 p = *(const float4*)(src + (size_t)(in0 + r) * DIMC + out0 + c4);
        T[r][c4] = p.x; T[r][c4 + 1] = p.y; T[r][c4 + 2] = p.z; T[r][c4 + 3] = p.w;
    }
    __syncthreads();
    #pragma unroll
    for (int l = 0; l < 2; l++) {
        int u = tid + (l << 8);
        int r = u >> 3, c8 = (u & 7) << 3;
        u16 e[8];
        #pragma unroll
        for (int i = 0; i < 8; i++) e[i] = f2bf(T[c8 + i][r] * scale);
        *(uint4*)(dst + (size_t)(out0 + r) * DIMC + in0 + c8) = *(uint4*)e;
    }
}

// ---------------------------------------------------------------------------
// Bias diagonal blocks + column padding into repacked layout.
// ---------------------------------------------------------------------------
__global__ __launch_bounds__(256) void bias_diag(
    const float* __restrict__ rpb, const float* __restrict__ rpbt,
    const int* __restrict__ tidx, const int* __restrict__ gidx,
    u16* __restrict__ bias)
{
    int j = blockIdx.x * 256 + threadIdx.x;   // 0..767
    int i = blockIdx.y;
    if (j >= 768) return;
    u16 vals[NHEAD];
    if (j >= NTOK) {
        u16 neg = f2bf(-1e30f);
        #pragma unroll
        for (int h = 0; h < NHEAD; h++) vals[h] = neg;
    } else if (i < NTMP && j < NTMP) {
        int idx = tidx[i * NTMP + j];
        #pragma unroll
        for (int h = 0; h < NHEAD; h++) vals[h] = f2bf(rpbt[idx * NHEAD + h]);
    } else if (i >= NTMP && j >= NTMP) {
        int idx = gidx[(i - NTMP) * NTGT + (j - NTMP)];
        #pragma unroll
        for (int h = 0; h < NHEAD; h++) vals[h] = f2bf(rpb[idx * NHEAD + h]);
    } else {
        return;  // cross region handled by bias_cross
    }
    #pragma unroll
    for (int h = 0; h < NHEAD; h++) bias[b2off(h, i, j)] = vals[h];
}

// ---------------------------------------------------------------------------
// Cross-bias MLP, computed once per (g,t), scattered to both cross blocks.
// ---------------------------------------------------------------------------
__global__ __launch_bounds__(256) void bias_cross(
    const float* __restrict__ w1, const float* __restrict__ b1,
    const float* __restrict__ w2, const float* __restrict__ b2,
    const float* __restrict__ tab, u16* __restrict__ bias)
{
    int g = blockIdx.x, t = threadIdx.x;
    float a  = tab[(g * NTMP + t) * 2 + 0];
    float bb = tab[(g * NTMP + t) * 2 + 1];
    float acc[NHEAD];
    #pragma unroll
    for (int h = 0; h < NHEAD; h++) acc[h] = b2[h];
    for (int k = 0; k < 512; k++) {
        float hid = fmaxf(a * w1[k] + bb * w1[512 + k] + b1[k], 0.0f);
        #pragma unroll
        for (int h = 0; h < NHEAD; h++) acc[h] += hid * w2[k * NHEAD + h];
    }
    #pragma unroll
    for (int h = 0; h < NHEAD; h++) {
        u16 v = f2bf(acc[h]);
        bias[b2off(h, t, NTMP + g)] = v;   // top-right
        bias[b2off(h, NTMP + g, t)] = v;   // bottom-left
    }
}

// ---------------------------------------------------------------------------
// bf16 MFMA GEMM, m97 shape: BM=BN=128, BK=64, chunk-major LDS, gl_lds width16.
// MODE 0: out bf16 -> C0. MODE 1 (KV fused, N=1536): n<768 -> C0, else C1.
// MODE 2: out fp32 + pb -> Cf.
// ---------------------------------------------------------------------------
template<int MODE>
__global__ __launch_bounds__(256) void gemm_bf16(
    const u16* __restrict__ A, const u16* __restrict__ Wt,
    const float* __restrict__ pb, u16* __restrict__ C0,
    u16* __restrict__ C1, float* __restrict__ Cf)
{
    __shared__ __align__(16) u16 As[8192];   // [chunk(8)][row(128)][8]
    __shared__ __align__(16) u16 Bs[8192];
    const int tid = threadIdx.x;
    const int lane = tid & 63, w = tid >> 6;
    const int quad = lane >> 4, ln = lane & 15;
    const int m0 = blockIdx.y << 7, n0g = blockIdx.x << 7;
    const int wm = (w >> 1) << 6, wn = (w & 1) << 6;
    const u16* Wbase = Wt + (size_t)n0g * DIMC;

    f32x4 acc[4][4];
    #pragma unroll
    for (int i = 0; i < 4; i++)
        #pragma unroll
        for (int j = 0; j < 4; j++)
            acc[i][j] = (f32x4){0.f, 0.f, 0.f, 0.f};

    for (int k0 = 0; k0 < DIMC; k0 += 64) {
        __syncthreads();
        #pragma unroll
        for (int l = 0; l < 4; l++) {
            int f = tid + (l << 8);          // 0..1023
            int c8 = f >> 7, r = f & 127;
            int grow = m0 + r; if (grow >= MROWS) grow = MROWS - 1;
            gl_lds16(A + (size_t)grow * DIMC + k0 + c8 * 8, As + f * 8);
            gl_lds16(Wbase + (size_t)r * DIMC + k0 + c8 * 8, Bs + f * 8);
        }
        __syncthreads();
        #pragma unroll
        for (int kp = 0; kp < 2; kp++) {
            bf16x8 af[4], bfr[4];
            #pragma unroll
            for (int mt = 0; mt < 4; mt++)
                af[mt] = *(const bf16x8*)&As[(((kp << 2) + quad) * 128 + wm + mt * 16 + ln) * 8];
            #pragma unroll
            for (int nt = 0; nt < 4; nt++)
                bfr[nt] = *(const bf16x8*)&Bs[(((kp << 2) + quad) * 128 + wn + nt * 16 + ln) * 8];
            #pragma unroll
            for (int mt = 0; mt < 4; mt++)
                #pragma unroll
                for (int nt = 0; nt < 4; nt++)
                    acc[mt][nt] = __builtin_amdgcn_mfma_f32_16x16x32_bf16(
                        af[mt], bfr[nt], acc[mt][nt], 0, 0, 0);
        }
    }

    u16* Cb = C0;
    int col0 = n0g;
    if (MODE == 1 && n0g >= DIMC) { Cb = C1; col0 = n0g - DIMC; }

    #pragma unroll
    for (int mt = 0; mt < 4; mt++) {
        #pragma unroll
        for (int reg = 0; reg < 4; reg++) {
            int grow = m0 + wm + mt * 16 + (quad << 2) + reg;
            if (grow >= MROWS) continue;
            #pragma unroll
            for (int nt = 0; nt < 4; nt++) {
                int gcol = col0 + wn + nt * 16 + ln;
                float v = acc[mt][nt][reg];
                if (MODE == 2) {
                    Cf[(size_t)grow * DIMC + gcol] = v + pb[gcol];
                } else {
                    Cb[(size_t)grow * DIMC + gcol] = f2bf(v);
                }
            }
        }
    }
}

// ---------------------------------------------------------------------------
// Flash MFMA attention, fixed-max softmax. 128 Q-rows/block; each wave owns
// two independent 16-row m-frags (ILP). K staged via global_load_lds
// chunk-major; V transposed into odd-stride LDS. grid (6, 12, 16).
// Q weights pre-scaled 0.125, so S = QK^T + bias directly.
// ---------------------------------------------------------------------------
__global__ __launch_bounds__(256) void attn_mfma(
    const u16* __restrict__ Qg, const u16* __restrict__ Kg,
    const u16* __restrict__ Vg, const u16* __restrict__ bias,
    u16* __restrict__ ctx)
{
    __shared__ __align__(16) u16 KsL[4096];        // [chunk(8)][jr(64)][8]
    __shared__ __align__(16) u16 VtL[64 * VSTR];   // [d][j], stride 66
    __shared__ __align__(16) u16 Pw[8][16][72];    // [w*2+mi][row][col]

    const int tid = threadIdx.x;
    const int lane = tid & 63, w = tid >> 6;
    const int quad = lane >> 4, ln = lane & 15;
    const int b = blockIdx.z, h = blockIdx.y;
    const int q0 = blockIdx.x << 7;
    const int mbase = q0 + (w << 5);               // wave's 32 rows
    const u16* bp = bias + ((size_t)h * NTOK) * 768;

    // Q fragments for both m-frags (A-layout), held for the whole kernel
    bf16x8 aq[2][2];
    #pragma unroll
    for (int mi = 0; mi < 2; mi++) {
        int qrow = mbase + (mi << 4) + ln; if (qrow >= NTOK) qrow = NTOK - 1;
        #pragma unroll
        for (int kp = 0; kp < 2; kp++)
            aq[mi][kp] = *(const bf16x8*)(Qg + ((size_t)(b * NTOK + qrow)) * DIMC
                                          + h * HDIM + kp * 32 + (quad << 3));
    }
    // bias row offsets (per m-frag, per acc reg)
    int boff[2][4];
    #pragma unroll
    for (int mi = 0; mi < 2; mi++)
        #pragma unroll
        for (int reg = 0; reg < 4; reg++) {
            int rr = mbase + (mi << 4) + (quad << 2) + reg;
            if (rr >= NTOK) rr = NTOK - 1;
            boff[mi][reg] = rr * 768 + (ln << 2);
        }

    float rs[2][4] = {};
    f32x4 O[2][4];
    #pragma unroll
    for (int mi = 0; mi < 2; mi++)
        #pragma unroll
        for (int dt = 0; dt < 4; dt++) O[mi][dt] = (f32x4){0.f, 0.f, 0.f, 0.f};

    for (int j0 = 0; j0 < NTOK; j0 += 64) {
        __syncthreads();
        // K tile via async global->LDS, chunk-major
        #pragma unroll
        for (int l = 0; l < 2; l++) {
            int f = tid + (l << 8);                // 0..511
            int chunk = f >> 6, jr = f & 63;
            int krow = j0 + jr; if (krow >= NTOK) krow = NTOK - 1;
            gl_lds16(Kg + ((size_t)(b * NTOK + krow)) * DIMC + h * HDIM + chunk * 8,
                     KsL + f * 8);
        }
        // bias prefetch into registers (overlaps QK MFMAs)
        uint2 bvv[2][4];
        #pragma unroll
        for (int mi = 0; mi < 2; mi++)
            #pragma unroll
            for (int reg = 0; reg < 4; reg++)
                bvv[mi][reg] = *(const uint2*)(bp + boff[mi][reg] + j0);
        // V tile transposed into odd-stride LDS
        #pragma unroll
        for (int l = 0; l < 2; l++) {
            int u = tid + (l << 8);
            int jr = u >> 3, d0 = (u & 7) << 3;
            int vrow = j0 + jr; if (vrow >= NTOK) vrow = NTOK - 1;
            uint4 p = *(const uint4*)(Vg + ((size_t)(b * NTOK + vrow)) * DIMC + h * HDIM + d0);
            const u16* pe = (const u16*)&p;
            #pragma unroll
            for (int i = 0; i < 8; i++) VtL[(d0 + i) * VSTR + jr] = pe[i];
        }
        __syncthreads();

        // V B-frags (shared by both m-frags): 4x b32 reads (odd stride)
        bf16x8 bv[4][2];
        #pragma unroll
        for (int dt = 0; dt < 4; dt++)
            #pragma unroll
            for (int kp = 0; kp < 2; kp++) {
                const unsigned int* vp = (const unsigned int*)
                    &VtL[(dt * 16 + ln) * VSTR + kp * 32 + (quad << 3)];
                uint4 vv; vv.x = vp[0]; vv.y = vp[1]; vv.z = vp[2]; vv.w = vp[3];
                bv[dt][kp] = *(const bf16x8*)&vv;
            }

        #pragma unroll
        for (int mi = 0; mi < 2; mi++) {
            // S = (Q/8) K^T
            f32x4 s[4];
            #pragma unroll
            for (int nt = 0; nt < 4; nt++) {
                f32x4 c = (f32x4){0.f, 0.f, 0.f, 0.f};
                #pragma unroll
                for (int kp = 0; kp < 2; kp++) {
                    bf16x8 bk = *(const bf16x8*)
                        &KsL[(((kp << 2) + quad) * 64 + nt * 16 + ln) * 8];
                    c = __builtin_amdgcn_mfma_f32_16x16x32_bf16(aq[mi][kp], bk, c, 0, 0, 0);
                }
                s[nt] = c;
            }
            // + bias, exp(s - SMAX), accumulate row sums
            #pragma unroll
            for (int reg = 0; reg < 4; reg++) {
                uint2 bb = bvv[mi][reg];
                float p0 = __expf(s[0][reg] + bflo(bb.x) - SMAX);
                float p1 = __expf(s[1][reg] + bfhi(bb.x) - SMAX);
                float p2 = __expf(s[2][reg] + bflo(bb.y) - SMAX);
                float p3 = __expf(s[3][reg] + bfhi(bb.y) - SMAX);
                s[0][reg] = p0; s[1][reg] = p1; s[2][reg] = p2; s[3][reg] = p3;
                rs[mi][reg] += p0 + p1 + p2 + p3;
            }
            // P: C-layout -> A-layout through wave-private LDS
            #pragma unroll
            for (int nt = 0; nt < 4; nt++)
                #pragma unroll
                for (int reg = 0; reg < 4; reg++)
                    Pw[(w << 1) + mi][(quad << 2) + reg][nt * 16 + ln] = f2bf(s[nt][reg]);
            bf16x8 ap[2];
            #pragma unroll
            for (int kp = 0; kp < 2; kp++)
                ap[kp] = *(const bf16x8*)&Pw[(w << 1) + mi][ln][kp * 32 + (quad << 3)];
            // O += P V
            #pragma unroll
            for (int dt = 0; dt < 4; dt++)
                #pragma unroll
                for (int kp = 0; kp < 2; kp++)
                    O[mi][dt] = __builtin_amdgcn_mfma_f32_16x16x32_bf16(
                        ap[kp], bv[dt][kp], O[mi][dt], 0, 0, 0);
        }
    }

    // normalize + store
    #pragma unroll
    for (int mi = 0; mi < 2; mi++) {
        #pragma unroll
        for (int reg = 0; reg < 4; reg++) {
            float t = rs[mi][reg];
            #pragma unroll
            for (int mk = 8; mk >= 1; mk >>= 1) t += __shfl_xor(t, mk);
            float inv = 1.0f / t;
            int row = mbase + (mi << 4) + (quad << 2) + reg;
            if (row < NTOK) {
                #pragma unroll
                for (int dt = 0; dt < 4; dt++)
                    ctx[((size_t)(b * NTOK + row)) * DIMC + h * HDIM + dt * 16 + ln]
                        = f2bf(O[mi][dt][reg] * inv);
            }
        }
    }
}

// ---------------------------------------------------------------------------
extern "C" void kernel_launch(void* const* d_in, const int* in_sizes, int n_in,
                              void* d_out, int out_size, void* d_ws, size_t ws_size,
                              hipStream_t stream)
{
    const float* x        = (const float*)d_in[0];
    const float* temp_q   = (const float*)d_in[1];
    const float* target_q = (const float*)d_in[2];
    const float* q_w      = (const float*)d_in[3];
    const float* k_w      = (const float*)d_in[4];
    const float* v_w      = (const float*)d_in[5];
    const float* proj_w   = (const float*)d_in[6];
    const float* proj_b   = (const float*)d_in[7];
    const float* rpb      = (const float*)d_in[8];
    const float* rpbt     = (const float*)d_in[9];
    const float* pw1      = (const float*)d_in[10];
    const float* pb1      = (const float*)d_in[11];
    const float* pw2      = (const float*)d_in[12];
    const float* pb2      = (const float*)d_in[13];
    const float* tab      = (const float*)d_in[14];
    const int*   tidx     = (const int*)d_in[15];
    const int*   gidx     = (const int*)d_in[16];
    float* out = (float*)d_out;

    char* ws = (char*)d_ws;
    const size_t S = (size_t)MROWS * DIMC * sizeof(u16);          // 18,186,240
    const size_t SZB = (size_t)NHEAD * NTOK * 768 * sizeof(u16);  // 13,639,680
    u16* XB    = (u16*)(ws);           // also CTX (aliased, after KV gemm)
    u16* QB    = (u16*)(ws + S);       // also V (aliased, after Q gemm)
    u16* Q     = (u16*)(ws + 2 * S);
    u16* K     = (u16*)(ws + 3 * S);
    u16* V     = QB;
    u16* CTX   = XB;
    u16* BIAS2 = (u16*)(ws + 4 * S);
    u16* WT    = (u16*)(ws + 4 * S + SZB);                        // 4 x 768 x 768

    convert_qx<<<dim3(4440), 256, 0, stream>>>(x, temp_q, target_q, XB, QB);
    transpose_w<<<dim3(12, 12, 4), 256, 0, stream>>>(q_w, k_w, v_w, proj_w, WT);
    bias_diag<<<dim3(3, 740), 256, 0, stream>>>(rpb, rpbt, tidx, gidx, BIAS2);
    bias_cross<<<dim3(484), 256, 0, stream>>>(pw1, pb1, pw2, pb2, tab, BIAS2);

    const u16* WTq = WT;
    const u16* WTkv = WT + (size_t)DIMC * DIMC;       // k plane, v plane adjacent
    const u16* WTp = WT + 3 * (size_t)DIMC * DIMC;

    gemm_bf16<0><<<dim3(6, 93), 256, 0, stream>>>(QB, WTq, nullptr, Q, nullptr, nullptr);
    gemm_bf16<1><<<dim3(12, 93), 256, 0, stream>>>(XB, WTkv, nullptr, K, V, nullptr);
    attn_mfma<<<dim3(6, 12, 16), 256, 0, stream>>>(Q, K, V, BIAS2, CTX);
    gemm_bf16<2><<<dim3(6, 93), 256, 0, stream>>>(CTX, WTp, proj_b, nullptr, nullptr, out);
}

// Round 7
// 495.764 us; speedup vs baseline: 1.1746x; 1.0215x over previous
//
#include <hip/hip_runtime.h>

// Convattn: B=16, N=740 (256+484), C=768, H=12, hd=64. Inputs/outputs fp32.
// ws: XB/QB/Q/K/V/CTX bf16 (V aliases QB — safe ONLY because Q-GEMM and
// KV-GEMM are separate ordered launches; do NOT fuse them), BIAS2 bf16
// repacked [h][row][jb][ln][nt], WT bf16 (q-plane pre-scaled 0.125).

typedef unsigned short u16;
typedef short bf16x8 __attribute__((ext_vector_type(8)));
typedef float f32x4 __attribute__((ext_vector_type(4)));

#define BSZ   16
#define NTOK  740
#define NTMP  256
#define NTGT  484
#define DIMC  768
#define NHEAD 12
#define HDIM  64
#define MROWS (BSZ*NTOK)      // 11840
#define SMAX  16.0f           // fixed softmax max (scores bounded ~|6|)

__device__ __forceinline__ float bf2f(u16 u) {
    return __uint_as_float(((unsigned int)u) << 16);
}
__device__ __forceinline__ float bflo(unsigned int u) {
    return __uint_as_float(u << 16);
}
__device__ __forceinline__ float bfhi(unsigned int u) {
    return __uint_as_float(u & 0xffff0000u);
}
__device__ __forceinline__ u16 f2bf(float f) {
    unsigned int u = __float_as_uint(f);
    u += 0x7fffu + ((u >> 16) & 1u);   // RNE
    return (u16)(u >> 16);
}

// async 16B global -> LDS (gfx950). LDS dest must be wave base + lane*16.
__device__ __forceinline__ void gl_lds16(const u16* g, u16* l) {
    __builtin_amdgcn_global_load_lds(
        (const __attribute__((address_space(1))) unsigned int*)(unsigned long long)g,
        (__attribute__((address_space(3))) unsigned int*)(unsigned int)(unsigned long long)l,
        16, 0, 0);
}

// repacked bias offset: [h][i][jb][ln][nt]
__device__ __forceinline__ size_t b2off(int h, int i, int j) {
    return ((size_t)(h * NTOK + i)) * 768 + ((j >> 6) << 6) + ((j & 15) << 2) + ((j >> 4) & 3);
}

// ---------------------------------------------------------------------------
// Fused prep kernel: block ranges do convert / weight-transpose / bias-diag /
// bias-cross. All outputs disjoint. grid = 4440 + 576 + 2220 + 484 = 7720.
// ---------------------------------------------------------------------------
#define PREP_CONV 4440
#define PREP_TRW  (PREP_CONV + 576)
#define PREP_DIAG (PREP_TRW + 2220)
#define PREP_ALL  (PREP_DIAG + 484)

__global__ __launch_bounds__(256) void prep_kernel(
    const float* __restrict__ x, const float* __restrict__ tq,
    const float* __restrict__ gq, u16* __restrict__ XB, u16* __restrict__ QB,
    const float* __restrict__ w0, const float* __restrict__ w1,
    const float* __restrict__ w2, const float* __restrict__ w3,
    u16* __restrict__ Wt,
    const float* __restrict__ rpb, const float* __restrict__ rpbt,
    const int* __restrict__ tidx, const int* __restrict__ gidx,
    const float* __restrict__ pw1, const float* __restrict__ pb1,
    const float* __restrict__ pw2, const float* __restrict__ pb2,
    const float* __restrict__ tab, u16* __restrict__ bias)
{
    __shared__ float T[64][65];
    const int blk = blockIdx.x;
    const int tid = threadIdx.x;

    if (blk < PREP_CONV) {
        // ----- fp32 -> bf16 convert: XB, QB -----
        int c = blk * 256 + tid;
        {
            const float* s = x + (size_t)c * 8;
            float4 p0 = *(const float4*)s, p1 = *(const float4*)(s + 4);
            u16 e[8] = {f2bf(p0.x), f2bf(p0.y), f2bf(p0.z), f2bf(p0.w),
                        f2bf(p1.x), f2bf(p1.y), f2bf(p1.z), f2bf(p1.w)};
            *(uint4*)(XB + (size_t)c * 8) = *(uint4*)e;
        }
        {
            int row = c / 96, cc = (c - row * 96) * 8;
            int b = row / NTOK, n = row - b * NTOK;
            const float* s = (n < NTMP)
                           ? tq + ((size_t)(b * NTMP + n)) * DIMC + cc
                           : gq + ((size_t)(b * NTGT + (n - NTMP))) * DIMC + cc;
            float4 p0 = *(const float4*)s, p1 = *(const float4*)(s + 4);
            u16 e[8] = {f2bf(p0.x), f2bf(p0.y), f2bf(p0.z), f2bf(p0.w),
                        f2bf(p1.x), f2bf(p1.y), f2bf(p1.z), f2bf(p1.w)};
            *(uint4*)(QB + (size_t)row * DIMC + cc) = *(uint4*)e;
        }
    } else if (blk < PREP_TRW) {
        // ----- weight transpose + bf16 (z=0 scaled 1/8) -----
        int t = blk - PREP_CONV;          // 0..575
        int z = t / 144, rem = t - z * 144;
        int bx = rem % 12, by = rem / 12;
        const float* src = (z == 0) ? w0 : (z == 1) ? w1 : (z == 2) ? w2 : w3;
        const float scale = (z == 0) ? 0.125f : 1.0f;
        u16* dst = Wt + (size_t)z * DIMC * DIMC;
        int out0 = bx * 64, in0 = by * 64;
        #pragma unroll
        for (int l = 0; l < 4; l++) {
            int u = tid + (l << 8);
            int r = u >> 4, c4 = (u & 15) << 2;
            float4 p = *(const float4*)(src + (size_t)(in0 + r) * DIMC + out0 + c4);
            T[r][c4] = p.x; T[r][c4 + 1] = p.y; T[r][c4 + 2] = p.z; T[r][c4 + 3] = p.w;
        }
        __syncthreads();
        #pragma unroll
        for (int l = 0; l < 2; l++) {
            int u = tid + (l << 8);
            int r = u >> 3, c8 = (u & 7) << 3;
            u16 e[8];
            #pragma unroll
            for (int i = 0; i < 8; i++) e[i] = f2bf(T[c8 + i][r] * scale);
            *(uint4*)(dst + (size_t)(out0 + r) * DIMC + in0 + c8) = *(uint4*)e;
        }
    } else if (blk < PREP_DIAG) {
        // ----- bias diagonal blocks + padding -----
        int t = blk - PREP_TRW;           // 0..2219
        int jb = t % 3, i = t / 3;
        int j = jb * 256 + tid;
        u16 vals[NHEAD];
        if (j >= NTOK) {
            u16 neg = f2bf(-1e30f);
            #pragma unroll
            for (int h = 0; h < NHEAD; h++) vals[h] = neg;
        } else if (i < NTMP && j < NTMP) {
            int idx = tidx[i * NTMP + j];
            #pragma unroll
            for (int h = 0; h < NHEAD; h++) vals[h] = f2bf(rpbt[idx * NHEAD + h]);
        } else if (i >= NTMP && j >= NTMP) {
            int idx = gidx[(i - NTMP) * NTGT + (j - NTMP)];
            #pragma unroll
            for (int h = 0; h < NHEAD; h++) vals[h] = f2bf(rpb[idx * NHEAD + h]);
        } else {
            return;  // cross region
        }
        #pragma unroll
        for (int h = 0; h < NHEAD; h++) bias[b2off(h, i, j)] = vals[h];
    } else {
        // ----- cross-bias MLP -----
        int g = blk - PREP_DIAG;          // 0..483
        int t = tid;                      // 0..255
        float a  = tab[(g * NTMP + t) * 2 + 0];
        float bb = tab[(g * NTMP + t) * 2 + 1];
        float acc[NHEAD];
        #pragma unroll
        for (int h = 0; h < NHEAD; h++) acc[h] = pb2[h];
        for (int k = 0; k < 512; k++) {
            float hid = fmaxf(a * pw1[k] + bb * pw1[512 + k] + pb1[k], 0.0f);
            #pragma unroll
            for (int h = 0; h < NHEAD; h++) acc[h] += hid * pw2[k * NHEAD + h];
        }
        #pragma unroll
        for (int h = 0; h < NHEAD; h++) {
            u16 v = f2bf(acc[h]);
            bias[b2off(h, t, NTMP + g)] = v;   // top-right
            bias[b2off(h, NTMP + g, t)] = v;   // bottom-left
        }
    }
}

// ---------------------------------------------------------------------------
// bf16 MFMA GEMM, m97 shape: BM=BN=128, BK=64, chunk-major LDS, gl_lds w16.
// MODE 0: out bf16 -> C0 (Wt = plane base).
// MODE 1: KV, grid x 0..11; Wt = k-plane (v adjacent): bx<6 -> C0(K), else C1(V).
// MODE 2: out fp32 + pb -> Cf.
// NOTE: MODE 0 (reads QB) and MODE 1 (writes V==QB) MUST be separate launches.
// ---------------------------------------------------------------------------
template<int MODE>
__global__ __launch_bounds__(256) void gemm_bf16(
    const u16* __restrict__ A, const u16* __restrict__ Wt,
    const float* __restrict__ pb, u16* __restrict__ C0,
    u16* __restrict__ C1, float* __restrict__ Cf)
{
    __shared__ __align__(16) u16 As[8192];   // [chunk(8)][row(128)][8]
    __shared__ __align__(16) u16 Bs[8192];
    const int tid = threadIdx.x;
    const int lane = tid & 63, w = tid >> 6;
    const int quad = lane >> 4, ln = lane & 15;
    const int m0 = blockIdx.y << 7;
    const int wm = (w >> 1) << 6, wn = (w & 1) << 6;

    const int nn = blockIdx.x << 7;
    const u16* Wbase = Wt + (size_t)nn * DIMC;
    u16* Cb;
    int col0;
    if (MODE == 1) {
        if (nn < DIMC) { col0 = nn; Cb = C0; }
        else           { col0 = nn - DIMC; Cb = C1; }
    } else {
        col0 = nn; Cb = C0;
    }

    f32x4 acc[4][4];
    #pragma unroll
    for (int i = 0; i < 4; i++)
        #pragma unroll
        for (int j = 0; j < 4; j++)
            acc[i][j] = (f32x4){0.f, 0.f, 0.f, 0.f};

    for (int k0 = 0; k0 < DIMC; k0 += 64) {
        __syncthreads();
        #pragma unroll
        for (int l = 0; l < 4; l++) {
            int f = tid + (l << 8);          // 0..1023
            int c8 = f >> 7, r = f & 127;
            int grow = m0 + r; if (grow >= MROWS) grow = MROWS - 1;
            gl_lds16(A + (size_t)grow * DIMC + k0 + c8 * 8, As + f * 8);
            gl_lds16(Wbase + (size_t)r * DIMC + k0 + c8 * 8, Bs + f * 8);
        }
        __syncthreads();
        #pragma unroll
        for (int kp = 0; kp < 2; kp++) {
            bf16x8 af[4], bfr[4];
            #pragma unroll
            for (int mt = 0; mt < 4; mt++)
                af[mt] = *(const bf16x8*)&As[(((kp << 2) + quad) * 128 + wm + mt * 16 + ln) * 8];
            #pragma unroll
            for (int nt = 0; nt < 4; nt++)
                bfr[nt] = *(const bf16x8*)&Bs[(((kp << 2) + quad) * 128 + wn + nt * 16 + ln) * 8];
            #pragma unroll
            for (int mt = 0; mt < 4; mt++)
                #pragma unroll
                for (int nt = 0; nt < 4; nt++)
                    acc[mt][nt] = __builtin_amdgcn_mfma_f32_16x16x32_bf16(
                        af[mt], bfr[nt], acc[mt][nt], 0, 0, 0);
        }
    }

    #pragma unroll
    for (int mt = 0; mt < 4; mt++) {
        #pragma unroll
        for (int reg = 0; reg < 4; reg++) {
            int grow = m0 + wm + mt * 16 + (quad << 2) + reg;
            if (grow >= MROWS) continue;
            #pragma unroll
            for (int nt = 0; nt < 4; nt++) {
                int gcol = col0 + wn + nt * 16 + ln;
                float v = acc[mt][nt][reg];
                if (MODE == 2) {
                    Cf[(size_t)grow * DIMC + gcol] = v + pb[gcol];
                } else {
                    Cb[(size_t)grow * DIMC + gcol] = f2bf(v);
                }
            }
        }
    }
}

// ---------------------------------------------------------------------------
// Flash MFMA attention, fixed-max softmax. 128 Q-rows/block; each wave owns
// two 16-row m-frags. K via gl_lds chunk-major; V transposed into
// XOR-swizzled stride-72 LDS (conflict-free writes, b128 reads); P round-trip
// likewise XOR-swizzled. grid (6, 12, 16).
// ---------------------------------------------------------------------------
__global__ __launch_bounds__(256) void attn_mfma(
    const u16* __restrict__ Qg, const u16* __restrict__ Kg,
    const u16* __restrict__ Vg, const u16* __restrict__ bias,
    u16* __restrict__ ctx)
{
    __shared__ __align__(16) u16 KsL[4096];        // [chunk(8)][jr(64)][8]
    __shared__ __align__(16) u16 VtL[64 * 72];     // [d][j^swz], stride 72
    __shared__ __align__(16) u16 Pw[8][16][72];    // [w*2+mi][m][k^swz]

    const int tid = threadIdx.x;
    const int lane = tid & 63, w = tid >> 6;
    const int quad = lane >> 4, ln = lane & 15;
    const int b = blockIdx.z, h = blockIdx.y;
    const int q0 = blockIdx.x << 7;
    const int mbase = q0 + (w << 5);               // wave's 32 rows
    const u16* bp = bias + ((size_t)h * NTOK) * 768;

    // Q fragments for both m-frags (A-layout), held for the whole kernel
    bf16x8 aq[2][2];
    #pragma unroll
    for (int mi = 0; mi < 2; mi++) {
        int qrow = mbase + (mi << 4) + ln; if (qrow >= NTOK) qrow = NTOK - 1;
        #pragma unroll
        for (int kp = 0; kp < 2; kp++)
            aq[mi][kp] = *(const bf16x8*)(Qg + ((size_t)(b * NTOK + qrow)) * DIMC
                                          + h * HDIM + kp * 32 + (quad << 3));
    }
    int boff[2][4];
    #pragma unroll
    for (int mi = 0; mi < 2; mi++)
        #pragma unroll
        for (int reg = 0; reg < 4; reg++) {
            int rr = mbase + (mi << 4) + (quad << 2) + reg;
            if (rr >= NTOK) rr = NTOK - 1;
            boff[mi][reg] = rr * 768 + (ln << 2);
        }

    // P read swizzle constant (row = ln)
    const int pswz = ((ln >> 2) & 3) << 4;

    float rs[2][4] = {};
    f32x4 O[2][4];
    #pragma unroll
    for (int mi = 0; mi < 2; mi++)
        #pragma unroll
        for (int dt = 0; dt < 4; dt++) O[mi][dt] = (f32x4){0.f, 0.f, 0.f, 0.f};

    for (int j0 = 0; j0 < NTOK; j0 += 64) {
        __syncthreads();
        // K tile via async global->LDS, chunk-major
        #pragma unroll
        for (int l = 0; l < 2; l++) {
            int f = tid + (l << 8);                // 0..511
            int chunk = f >> 6, jr = f & 63;
            int krow = j0 + jr; if (krow >= NTOK) krow = NTOK - 1;
            gl_lds16(Kg + ((size_t)(b * NTOK + krow)) * DIMC + h * HDIM + chunk * 8,
                     KsL + f * 8);
        }
        // bias prefetch into registers
        uint2 bvv[2][4];
        #pragma unroll
        for (int mi = 0; mi < 2; mi++)
            #pragma unroll
            for (int reg = 0; reg < 4; reg++)
                bvv[mi][reg] = *(const uint2*)(bp + boff[mi][reg] + j0);
        // V tile transposed into XOR-swizzled LDS: elem V^T[d][j] at
        // d*72 + (j ^ ((d>>3)&7)*8)
        #pragma unroll
        for (int l = 0; l < 2; l++) {
            int u = tid + (l << 8);
            int jr = u >> 3, d0 = (u & 7) << 3;
            int vrow = j0 + jr; if (vrow >= NTOK) vrow = NTOK - 1;
            uint4 p = *(const uint4*)(Vg + ((size_t)(b * NTOK + vrow)) * DIMC + h * HDIM + d0);
            const u16* pe = (const u16*)&p;
            int jswz = jr ^ d0;                   // key = d0 (multiple of 8, <64)
            #pragma unroll
            for (int i = 0; i < 8; i++) VtL[(d0 + i) * 72 + jswz] = pe[i];
        }
        __syncthreads();

        // V B-frags (shared by both m-frags), b128 via swizzled offset
        bf16x8 bv[4][2];
        #pragma unroll
        for (int dt = 0; dt < 4; dt++) {
            int key8 = ((dt * 2 + (ln >> 3)) & 7) << 3;
            #pragma unroll
            for (int kp = 0; kp < 2; kp++) {
                int koff = (kp * 32 + (quad << 3)) ^ key8;
                bv[dt][kp] = *(const bf16x8*)&VtL[(dt * 16 + ln) * 72 + koff];
            }
        }

        // S = (Q/8) K^T, K-frags read once, both m-frags interleaved
        f32x4 s[2][4];
        #pragma unroll
        for (int mi = 0; mi < 2; mi++)
            #pragma unroll
            for (int nt = 0; nt < 4; nt++) s[mi][nt] = (f32x4){0.f, 0.f, 0.f, 0.f};
        #pragma unroll
        for (int kp = 0; kp < 2; kp++)
            #pragma unroll
            for (int nt = 0; nt < 4; nt++) {
                bf16x8 bk = *(const bf16x8*)
                    &KsL[(((kp << 2) + quad) * 64 + nt * 16 + ln) * 8];
                s[0][nt] = __builtin_amdgcn_mfma_f32_16x16x32_bf16(aq[0][kp], bk, s[0][nt], 0, 0, 0);
                s[1][nt] = __builtin_amdgcn_mfma_f32_16x16x32_bf16(aq[1][kp], bk, s[1][nt], 0, 0, 0);
            }

        #pragma unroll
        for (int mi = 0; mi < 2; mi++) {
            // + bias, exp(s - SMAX), accumulate row sums
            #pragma unroll
            for (int reg = 0; reg < 4; reg++) {
                uint2 bb = bvv[mi][reg];
                float p0 = __expf(s[mi][0][reg] + bflo(bb.x) - SMAX);
                float p1 = __expf(s[mi][1][reg] + bfhi(bb.x) - SMAX);
                float p2 = __expf(s[mi][2][reg] + bflo(bb.y) - SMAX);
                float p3 = __expf(s[mi][3][reg] + bfhi(bb.y) - SMAX);
                s[mi][0][reg] = p0; s[mi][1][reg] = p1;
                s[mi][2][reg] = p2; s[mi][3][reg] = p3;
                rs[mi][reg] += p0 + p1 + p2 + p3;
            }
            // P: C-layout -> A-layout through swizzled wave-private LDS:
            // write row quad*4+reg, col (nt^quad)*16 + ln
            u16* pwb = &Pw[(w << 1) + mi][0][0];
            #pragma unroll
            for (int nt = 0; nt < 4; nt++) {
                int colw = ((nt ^ quad) << 4) + ln;
                #pragma unroll
                for (int reg = 0; reg < 4; reg++)
                    pwb[((quad << 2) + reg) * 72 + colw] = f2bf(s[mi][nt][reg]);
            }
            bf16x8 ap[2];
            #pragma unroll
            for (int kp = 0; kp < 2; kp++) {
                int koff = (kp * 32 + (quad << 3)) ^ pswz;
                ap[kp] = *(const bf16x8*)&pwb[ln * 72 + koff];
            }
            // O += P V
            #pragma unroll
            for (int dt = 0; dt < 4; dt++)
                #pragma unroll
                for (int kp = 0; kp < 2; kp++)
                    O[mi][dt] = __builtin_amdgcn_mfma_f32_16x16x32_bf16(
                        ap[kp], bv[dt][kp], O[mi][dt], 0, 0, 0);
        }
    }

    // normalize + store
    #pragma unroll
    for (int mi = 0; mi < 2; mi++) {
        #pragma unroll
        for (int reg = 0; reg < 4; reg++) {
            float t = rs[mi][reg];
            #pragma unroll
            for (int mk = 8; mk >= 1; mk >>= 1) t += __shfl_xor(t, mk);
            float inv = 1.0f / t;
            int row = mbase + (mi << 4) + (quad << 2) + reg;
            if (row < NTOK) {
                #pragma unroll
                for (int dt = 0; dt < 4; dt++)
                    ctx[((size_t)(b * NTOK + row)) * DIMC + h * HDIM + dt * 16 + ln]
                        = f2bf(O[mi][dt][reg] * inv);
            }
        }
    }
}

// ---------------------------------------------------------------------------
extern "C" void kernel_launch(void* const* d_in, const int* in_sizes, int n_in,
                              void* d_out, int out_size, void* d_ws, size_t ws_size,
                              hipStream_t stream)
{
    const float* x        = (const float*)d_in[0];
    const float* temp_q   = (const float*)d_in[1];
    const float* target_q = (const float*)d_in[2];
    const float* q_w      = (const float*)d_in[3];
    const float* k_w      = (const float*)d_in[4];
    const float* v_w      = (const float*)d_in[5];
    const float* proj_w   = (const float*)d_in[6];
    const float* proj_b   = (const float*)d_in[7];
    const float* rpb      = (const float*)d_in[8];
    const float* rpbt     = (const float*)d_in[9];
    const float* pw1      = (const float*)d_in[10];
    const float* pb1      = (const float*)d_in[11];
    const float* pw2      = (const float*)d_in[12];
    const float* pb2      = (const float*)d_in[13];
    const float* tab      = (const float*)d_in[14];
    const int*   tidx     = (const int*)d_in[15];
    const int*   gidx     = (const int*)d_in[16];
    float* out = (float*)d_out;

    char* ws = (char*)d_ws;
    const size_t S = (size_t)MROWS * DIMC * sizeof(u16);          // 18,186,240
    const size_t SZB = (size_t)NHEAD * NTOK * 768 * sizeof(u16);  // 13,639,680
    u16* XB    = (u16*)(ws);           // also CTX (aliased, after KV gemm)
    u16* QB    = (u16*)(ws + S);       // also V (aliased, after Q gemm)
    u16* Q     = (u16*)(ws + 2 * S);
    u16* K     = (u16*)(ws + 3 * S);
    u16* V     = QB;
    u16* CTX   = XB;
    u16* BIAS2 = (u16*)(ws + 4 * S);
    u16* WT    = (u16*)(ws + 4 * S + SZB);                        // 4 x 768 x 768

    prep_kernel<<<dim3(PREP_ALL), 256, 0, stream>>>(
        x, temp_q, target_q, XB, QB,
        q_w, k_w, v_w, proj_w, WT,
        rpb, rpbt, tidx, gidx,
        pw1, pb1, pw2, pb2, tab, BIAS2);

    const u16* WTq = WT;
    const u16* WTk = WT + (size_t)DIMC * DIMC;    // k plane (v plane adjacent)
    const u16* WTp = WT + 3 * (size_t)DIMC * DIMC;

    gemm_bf16<0><<<dim3(6, 93), 256, 0, stream>>>(QB, WTq, nullptr, Q, nullptr, nullptr);
    gemm_bf16<1><<<dim3(12, 93), 256, 0, stream>>>(XB, WTk, nullptr, K, V, nullptr);
    attn_mfma<<<dim3(6, 12, 16), 256, 0, stream>>>(Q, K, V, BIAS2, CTX);
    gemm_bf16<2><<<dim3(6, 93), 256, 0, stream>>>(CTX, WTp, proj_b, nullptr, nullptr, out);
}